// Round 6
// baseline (806.885 us; speedup 1.0000x reference)
//
#include <hip/hip_runtime.h>
#include <hip/hip_fp16.h>

#define DI __device__ __forceinline__

typedef _Float16 f16x8 __attribute__((ext_vector_type(8)));
typedef float f32x4 __attribute__((ext_vector_type(4)));

struct alignas(8) h4 { __half x, y, z, w; };

DI void async16(const void* g, void* l) {
  __builtin_amdgcn_global_load_lds(
      (__attribute__((address_space(1))) void*)g,
      (__attribute__((address_space(3))) void*)l, 16, 0, 0);
}

DI float waveReduceSum(float v) {
#pragma unroll
  for (int i = 1; i < 64; i <<= 1) v += __shfl_xor(v, i);
  return v;
}
DI float waveReduceMax(float v) {
#pragma unroll
  for (int i = 1; i < 64; i <<= 1) v = fmaxf(v, __shfl_xor(v, i));
  return v;
}

DI float gelu_exact(float x) { return 0.5f * x * (1.f + erff(x * 0.70710678118654752f)); }

// ---------------------------------------------------------------------------
// GEMM: C[M,N] = A[M,K] * Bt[N,K]^T (+bias), fp16 in, fp32 acc.
// 128x128 tile, 256 threads (2x2 waves, each 4x4 of 16x16x32 MFMA).
// Ping-pong pipeline: BK=32 per stage, 2 stages (32 KB LDS total), ONE barrier
// per iteration; async global_load_lds for stage s+1 issued right after the
// barrier and drained at the NEXT barrier — load latency overlapped with the
// 16-MFMA compute phase instead of exposed (R5 post-mortem: barrier drain was
// the bottleneck, hbm 1.8 TB/s at MfmaUtil 26%).
// LDS XOR swizzle: row r (64 B), global chunk gc stored at slot gc^((r>>1)&3);
// read side worst case 2-way bank alias = free (m136).
// GROUP_M=8 block swizzle (R3-verified best for QK at z=1, nT=48).
// blockIdx.z: batch or split-K index via strides sA/sB/sC/sBias.
// ---------------------------------------------------------------------------
template <typename CT, bool BIAS, bool BROW>
__global__ __launch_bounds__(256) void gemm_nt(
    const __half* __restrict__ A, int lda, long long sA,
    const __half* __restrict__ Bt, int ldb, long long sB,
    const float* __restrict__ bias, long long sBias,
    CT* __restrict__ C, int ldc, long long sC,
    int nT, int K) {
  __shared__ __align__(16) __half As[2 * 128 * 32];  // 16 KB (2 stages x 8 KB)
  __shared__ __align__(16) __half Bs[2 * 128 * 32];  // 16 KB

  const int tid = threadIdx.x;
  const int wave = tid >> 6, lane = tid & 63;

  // GROUP_M=8 swizzled block decode
  const int gsz = 8 * nT;
  const int g = blockIdx.x / gsz, r = blockIdx.x % gsz;
  const int m0 = (g * 8 + (r & 7)) * 128;
  const int n0 = (r >> 3) * 128;

  A += (long long)blockIdx.z * sA;
  Bt += (long long)blockIdx.z * sB;
  C += (long long)blockIdx.z * sC;
  if constexpr (BIAS || BROW) bias += (long long)blockIdx.z * sBias;
  const int wm = wave & 1, wn = wave >> 1;

  f32x4 acc[4][4];
#pragma unroll
  for (int i = 0; i < 4; ++i)
#pragma unroll
    for (int jj = 0; jj < 4; ++jj) acc[i][jj] = (f32x4){0.f, 0.f, 0.f, 0.f};

  // staging: inst i of thread t fills chunk c = i*256+t -> row i*64+(t>>2),
  // slot t&3; content = global chunk (t&3)^((t>>3)&3)  [slot s of row r holds
  // global chunk s^((r>>1)&3)]
  const int srow = tid >> 2;
  const int gc = (tid & 3) ^ ((tid >> 3) & 3);
  const __half* Ag = A + (size_t)(m0 + srow) * lda + gc * 8;
  const __half* Ag1 = Ag + (size_t)64 * lda;
  const __half* Bg = Bt + (size_t)(n0 + srow) * ldb + gc * 8;
  const __half* Bg1 = Bg + (size_t)64 * ldb;
  char* AsW = (char*)As + wave * 1024;  // + stage*8192 + inst*4096 (+lane*16 by HW)
  char* BsW = (char*)Bs + wave * 1024;

  const int ml = lane & 15, q = lane >> 4;
  // fragment read: row*64 + (q ^ ((ml>>1)&3))*16 bytes within stage
  const int sw = (q ^ ((ml >> 1) & 3)) * 16;
  const int aoff = (wm * 64 + ml) * 64 + sw;
  const int boff = (wn * 64 + ml) * 64 + sw;

  const int iters = K >> 5;

  // prologue: stage 0 <- k=0
  async16(Ag, AsW);
  async16(Ag1, AsW + 4096);
  async16(Bg, BsW);
  async16(Bg1, BsW + 4096);
  Ag += 32; Ag1 += 32; Bg += 32; Bg1 += 32;

  int st = 0;
  for (int it = 0; it + 1 < iters; ++it) {
    __syncthreads();  // drains stage-st loads (issued one compute-phase ago)
    {  // prefetch next stage
      char* dA = AsW + ((st ^ 1) ? 8192 : 0);
      char* dB = BsW + ((st ^ 1) ? 8192 : 0);
      async16(Ag, dA);
      async16(Ag1, dA + 4096);
      async16(Bg, dB);
      async16(Bg1, dB + 4096);
      Ag += 32; Ag1 += 32; Bg += 32; Bg1 += 32;
    }
    {  // compute current stage
      const char* Ab = (const char*)As + (st ? 8192 : 0) + aoff;
      const char* Bb = (const char*)Bs + (st ? 8192 : 0) + boff;
      f16x8 af[4], bf[4];
#pragma unroll
      for (int i = 0; i < 4; ++i) {
        af[i] = *(const f16x8*)(Ab + i * 1024);
        bf[i] = *(const f16x8*)(Bb + i * 1024);
      }
#pragma unroll
      for (int i = 0; i < 4; ++i)
#pragma unroll
        for (int jn = 0; jn < 4; ++jn)
          acc[i][jn] = __builtin_amdgcn_mfma_f32_16x16x32_f16(af[i], bf[jn], acc[i][jn], 0, 0, 0);
    }
    st ^= 1;
  }
  __syncthreads();  // drain last stage
  {
    const char* Ab = (const char*)As + (st ? 8192 : 0) + aoff;
    const char* Bb = (const char*)Bs + (st ? 8192 : 0) + boff;
    f16x8 af[4], bf[4];
#pragma unroll
    for (int i = 0; i < 4; ++i) {
      af[i] = *(const f16x8*)(Ab + i * 1024);
      bf[i] = *(const f16x8*)(Bb + i * 1024);
    }
#pragma unroll
    for (int i = 0; i < 4; ++i)
#pragma unroll
      for (int jn = 0; jn < 4; ++jn)
        acc[i][jn] = __builtin_amdgcn_mfma_f32_16x16x32_f16(af[i], bf[jn], acc[i][jn], 0, 0, 0);
  }

  // epilogue: C/D layout col=lane&15, row=(lane>>4)*4+reg  [m89-verified]
#pragma unroll
  for (int jj = 0; jj < 4; ++jj) {
    const int col = n0 + wn * 64 + jj * 16 + ml;
    const float bcol = BIAS ? bias[col] : 0.f;
#pragma unroll
    for (int i = 0; i < 4; ++i) {
      const int row = m0 + wm * 64 + i * 16 + q * 4;
#pragma unroll
      for (int rr = 0; rr < 4; ++rr) {
        float v = acc[i][jj][rr] + bcol;
        if constexpr (BROW) v += bias[row + rr];
        if constexpr (sizeof(CT) == 4)
          C[(size_t)(row + rr) * ldc + col] = v;
        else
          C[(size_t)(row + rr) * ldc + col] = __float2half(v);
      }
    }
  }
}

// ---------------------------------------------------------------------------
// prep: all 6 weight transposes (fp32 -> fp16) + bias concat. grid (2305, 6).
// y=0..3: Wq,Wk,Wv,W1 [768,3072] -> [3072,768]; y=4,5: Wo,W2 [3072,768]->[768,3072].
// (x==2304, y==0): concat bq|bk.
// ---------------------------------------------------------------------------
__global__ __launch_bounds__(256) void prep(
    const float* __restrict__ Wq, const float* __restrict__ Wk,
    const float* __restrict__ Wv, const float* __restrict__ W1,
    const float* __restrict__ Wo, const float* __restrict__ W2,
    const float* __restrict__ bq, const float* __restrict__ bk,
    __half* __restrict__ wD, __half* __restrict__ wB, __half* __restrict__ wC,
    __half* __restrict__ wA, float* __restrict__ bqk) {
  if (blockIdx.x == 2304) {
    if (blockIdx.y == 0)
      for (int i = threadIdx.x; i < 3072; i += 256) {
        bqk[i] = bq[i];
        bqk[3072 + i] = bk[i];
      }
    return;
  }
  __shared__ float t[32][33];
  const int tx = threadIdx.x & 31, ty = threadIdx.x >> 5;
  if (blockIdx.y < 4) {
    const float* in;
    __half* out;
    switch (blockIdx.y) {
      case 0: in = Wq; out = wD; break;
      case 1: in = Wk; out = wD + 3072 * 768; break;
      case 2: in = Wv; out = wB; break;
      default: in = W1; out = wC; break;
    }
    const int cb = blockIdx.x % 96, rb = blockIdx.x / 96;  // C=3072, R=768
    const int c = cb * 32 + tx, r0 = rb * 32;
#pragma unroll
    for (int i = 0; i < 32; i += 8) t[ty + i][tx] = in[(size_t)(r0 + ty + i) * 3072 + c];
    __syncthreads();
    const int oc = r0 + tx, o0 = cb * 32;
#pragma unroll
    for (int i = 0; i < 32; i += 8)
      out[(size_t)(o0 + ty + i) * 768 + oc] = __float2half(t[tx][ty + i]);
  } else {
    const float* in = (blockIdx.y == 5) ? W2 : Wo;
    __half* out = wA + ((blockIdx.y == 5) ? 3072 * 768 : 0);
    const int cb = blockIdx.x % 24, rb = blockIdx.x / 24;  // C=768, R=3072
    const int c = cb * 32 + tx, r0 = rb * 32;
#pragma unroll
    for (int i = 0; i < 32; i += 8) t[ty + i][tx] = in[(size_t)(r0 + ty + i) * 768 + c];
    __syncthreads();
    const int oc = r0 + tx, o0 = cb * 32;
#pragma unroll
    for (int i = 0; i < 32; i += 8)
      out[(size_t)(o0 + ty + i) * 3072 + oc] = __float2half(t[tx][ty + i]);
  }
}

// ---------------------------------------------------------------------------
__global__ __launch_bounds__(256) void embed_pos_kernel(
    const int* __restrict__ x, const float* __restrict__ emb,
    float* __restrict__ y, __half* __restrict__ yh) {
  const int row = blockIdx.x;  // b*1024 + s
  const int s = row & 1023;
  const int tok = x[row];
  const float* ep = emb + (size_t)tok * 768;
  float* yp = y + (size_t)row * 768;
  __half* hp = yh + (size_t)row * 768;
  const float c = -13.287712379549449f / 768.f;  // -log2(10000)/768
  for (int d = threadIdx.x; d < 768; d += 256) {
    float ang = (float)s * exp2f((float)d * c);
    float pe = (d & 1) ? cosf(ang) : sinf(ang);
    float v = ep[d] + pe;
    yp[d] = v;
    hp[d] = __float2half(v);
  }
}

// Row softmax over 1024 fp32 logits -> fp16 probs. One block per row.
__global__ __launch_bounds__(256) void softmax_rows(
    const float* __restrict__ L, __half* __restrict__ P) {
  const size_t row = blockIdx.x;
  const float4 x = ((const float4*)(L + row * 1024))[threadIdx.x];
  const int wave = threadIdx.x >> 6, lane = threadIdx.x & 63;
  float m = fmaxf(fmaxf(x.x, x.y), fmaxf(x.z, x.w));
  m = waveReduceMax(m);
  __shared__ float sm[4];
  __shared__ float ssum[4];
  if (lane == 0) sm[wave] = m;
  __syncthreads();
  m = fmaxf(fmaxf(sm[0], sm[1]), fmaxf(sm[2], sm[3]));
  float e0 = expf(x.x - m), e1 = expf(x.y - m), e2 = expf(x.z - m), e3 = expf(x.w - m);
  float s = e0 + e1 + e2 + e3;
  s = waveReduceSum(s);
  if (lane == 0) ssum[wave] = s;
  __syncthreads();
  s = ssum[0] + ssum[1] + ssum[2] + ssum[3];
  const float inv = 1.f / s;
  h4 o{__float2half(e0 * inv), __float2half(e1 * inv), __float2half(e2 * inv),
       __float2half(e3 * inv)};
  ((h4*)(P + row * 1024))[threadIdx.x] = o;
}

// y += [gelu](p0 + p1 + bias[d]) in-place + layernorm2d partial sums.
template <bool GELU>
__global__ __launch_bounds__(256) void residual_stats(
    float* __restrict__ y, const float* __restrict__ p0, const float* __restrict__ p1,
    const float* __restrict__ bias, float2* __restrict__ partials) {
  const int b = blockIdx.y, chunk = blockIdx.x;
  const size_t base = (size_t)b * 786432 + (size_t)chunk * 8192;
  float4* yp = (float4*)(y + base);
  const float4* a0 = (const float4*)(p0 + base);
  const float4* a1 = (const float4*)(p1 + base);
  float s = 0.f, ss = 0.f;
#pragma unroll
  for (int it = 0; it < 8; ++it) {
    const int idx = it * 256 + threadIdx.x;
    const int d = (chunk * 8192 + it * 1024 + threadIdx.x * 4) % 768;  // mult of 4
    float4 yv = yp[idx];
    float4 v0 = a0[idx];
    float4 v1 = a1[idx];
    const float4 bv = *(const float4*)(bias + d);
    float ax = v0.x + v1.x + bv.x, ay = v0.y + v1.y + bv.y;
    float az = v0.z + v1.z + bv.z, aw = v0.w + v1.w + bv.w;
    if constexpr (GELU) {
      ax = gelu_exact(ax); ay = gelu_exact(ay);
      az = gelu_exact(az); aw = gelu_exact(aw);
    }
    float4 rr{yv.x + ax, yv.y + ay, yv.z + az, yv.w + aw};
    yp[idx] = rr;
    s += rr.x + rr.y + rr.z + rr.w;
    ss += rr.x * rr.x + rr.y * rr.y + rr.z * rr.z + rr.w * rr.w;
  }
  s = waveReduceSum(s);
  ss = waveReduceSum(ss);
  __shared__ float2 wr[4];
  const int wave = threadIdx.x >> 6, lane = threadIdx.x & 63;
  if (lane == 0) wr[wave] = make_float2(s, ss);
  __syncthreads();
  if (threadIdx.x == 0) {
    float S = wr[0].x + wr[1].x + wr[2].x + wr[3].x;
    float SS = wr[0].y + wr[1].y + wr[2].y + wr[3].y;
    partials[b * 96 + chunk] = make_float2(S, SS);
  }
}

// Finalize (reduce 96 partials in-block) + apply LN; grid 6144 (768 blocks/batch).
template <bool WB>
__global__ __launch_bounds__(256) void ln_apply(
    float* __restrict__ y, __half* __restrict__ yh, const float* __restrict__ w,
    const float* __restrict__ bb, const float2* __restrict__ partials) {
  const unsigned i4 = blockIdx.x * 256 + threadIdx.x;  // float4 index
  const unsigned i = i4 * 4;
  const unsigned b = i / 786432u;  // uniform per block (1024 floats/block)
  const int tid = threadIdx.x;
  float s = 0.f, ss = 0.f;
  if (tid < 96) {
    float2 p = partials[b * 96 + tid];
    s = p.x;
    ss = p.y;
  }
  s = waveReduceSum(s);
  ss = waveReduceSum(ss);
  __shared__ float2 wsum[4];
  if ((tid & 63) == 0) wsum[tid >> 6] = make_float2(s, ss);
  __syncthreads();
  const float S = wsum[0].x + wsum[1].x + wsum[2].x + wsum[3].x;
  const float SS = wsum[0].y + wsum[1].y + wsum[2].y + wsum[3].y;
  const float inv = 1.f / 786432.f;
  const float mean = S * inv;
  const float rstd = rsqrtf(SS * inv - mean * mean + 1e-5f);

  const unsigned e4 = (i - b * 786432u) >> 2;
  float4 yv = ((const float4*)y)[i4];
  const float4 wv = ((const float4*)w)[e4];
  const float4 bv = ((const float4*)bb)[e4];
  float4 rr;
  rr.x = (yv.x - mean) * rstd * wv.x + bv.x;
  rr.y = (yv.y - mean) * rstd * wv.y + bv.y;
  rr.z = (yv.z - mean) * rstd * wv.z + bv.z;
  rr.w = (yv.w - mean) * rstd * wv.w + bv.w;
  ((float4*)y)[i4] = rr;
  if constexpr (WB) {
    h4 o{__float2half(rr.x), __float2half(rr.y), __float2half(rr.z), __float2half(rr.w)};
    ((h4*)yh)[i4] = o;
  }
}

// ---------------------------------------------------------------------------
extern "C" void kernel_launch(void* const* d_in, const int* in_sizes, int n_in,
                              void* d_out, int out_size, void* d_ws, size_t ws_size,
                              hipStream_t stream) {
  const int* x = (const int*)d_in[0];
  const float* emb = (const float*)d_in[1];
  const float* Wq = (const float*)d_in[2];
  const float* bq = (const float*)d_in[3];
  const float* Wk = (const float*)d_in[4];
  const float* bk = (const float*)d_in[5];
  const float* Wv = (const float*)d_in[6];
  const float* bv = (const float*)d_in[7];
  const float* Wo = (const float*)d_in[8];
  const float* bo = (const float*)d_in[9];
  const float* W1 = (const float*)d_in[10];
  const float* b1 = (const float*)d_in[11];
  const float* W2 = (const float*)d_in[12];
  const float* b2 = (const float*)d_in[13];
  const float* ln1w = (const float*)d_in[14];
  const float* ln1b = (const float*)d_in[15];
  const float* ln2w = (const float*)d_in[16];
  const float* ln2b = (const float*)d_in[17];

  float* y = (float*)d_out;  // [8,1024,768] fp32 residual stream

  // ---- workspace map (liveness overlays), total 228,065,280 B (<= 228,071,488 R2-verified) ----
  char* ws = (char*)d_ws;
  __half* yh = (__half*)(ws + 0);           // 12.58 MB fp16 residual stream
  __half* qk = (__half*)(ws + 12582912);    // 100.66 MB [8192,6144] q|k interleaved
  __half* av = qk;                          //   av [8192,3072] fp16 (after logits)
  __half* f1 = qk;                          //   ffn hidden (after Wo)
  __half* vT = (__half*)(ws + 113246208);   // 50.33 MB v^T -> abuf (2x25.17 split-K)
  float* abuf = (float*)vT;
  float* Lg = (float*)(ws + 163577856);     // 33.55 MB logits fp32; pre-logits holds:
  __half* wD = (__half*)(ws + 163577856);   //   Wq^T|Wk^T 9.44 MB
  __half* wB = (__half*)(ws + 173015040);   //   Wv^T 4.72 MB
  float* bqk = (float*)(ws + 177733632);    //   bq|bk 24 KB
  float2* part = (float2*)(ws + 177758208); //   6 KB (written post-softmax)
  __half* Ph = (__half*)(ws + 197132288);   // 16.78 MB probs fp16
  __half* wA = (__half*)(ws + 213909504);   // 9.44 MB Wo^T|W2^T
  __half* wC = (__half*)(ws + 223346688);   // 4.72 MB W1^T
  const size_t WS_NEEDED = 228065280;
  if (ws_size < WS_NEEDED) return;  // fail loud rather than corrupt the queue

  const dim3 blk(256);
  const long long SH = 1024LL * 3072, SS = 1024LL * 1024;
  const long long SQK = 1024LL * 6144;
  float* p1 = abuf + 6291456;  // second split-K partial

  prep<<<dim3(2305, 6), blk, 0, stream>>>(Wq, Wk, Wv, W1, Wo, W2, bq, bk, wD, wB, wC, wA, bqk);
  embed_pos_kernel<<<dim3(8192), blk, 0, stream>>>(x, emb, y, yh);

  // qk = yh @ [Wq|Wk] + [bq|bk] : [8192,768] x [6144,768]^T (R3 config: z=1, nT=48)
  gemm_nt<__half, true, false><<<dim3(3072, 1, 1), blk, 0, stream>>>(
      yh, 768, 0, wD, 768, 0, bqk, 0, qk, 6144, 0, 48, 768);

  // vT[b][n][s] = sum_k Wv[k][n]*y[b][s][k] + bv[n]  (A=Wv^T, Bt=y batch, row bias)
  gemm_nt<__half, false, true><<<dim3(192, 1, 8), blk, 0, stream>>>(
      wB, 768, 0, yh, 768, 1024LL * 768, bv, 0, vT, 1024, SH, 8, 768);

  // logits = q k^T (fp32), per batch; q/k are column slices of qk (lda 6144)
  gemm_nt<float, false, false><<<dim3(64, 1, 8), blk, 0, stream>>>(
      qk, 6144, SQK, qk + 3072, 6144, SQK, nullptr, 0, Lg, 1024, SS, 8, 3072);

  softmax_rows<<<dim3(8192), blk, 0, stream>>>(Lg, Ph);

  // av = P @ V (Bt = v^T), per batch; av overlays qk (dead)
  gemm_nt<__half, false, false><<<dim3(192, 1, 8), blk, 0, stream>>>(
      Ph, 1024, SS, vT, 1024, SH, nullptr, 0, av, 3072, SH, 24, 1024);

  // a = av @ Wo (split-K=2, partials; bias bo added in residual) -> abuf over vT
  gemm_nt<float, false, false><<<dim3(384, 1, 2), blk, 0, stream>>>(
      av, 3072, 1536, wA, 3072, 1536, nullptr, 0, abuf, 768, 6291456, 6, 1536);

  // y = ln1(y + a + bo)
  residual_stats<false><<<dim3(96, 8), blk, 0, stream>>>(y, abuf, p1, bo, part);
  ln_apply<true><<<dim3(6144), blk, 0, stream>>>(y, yh, ln1w, ln1b, part);

  // f1 = y@W1 + b1 -> overlays av (dead)
  gemm_nt<__half, true, false><<<dim3(1536, 1, 1), blk, 0, stream>>>(
      yh, 768, 0, wC, 768, 0, b1, 0, f1, 3072, 0, 24, 768);
  // f = f1@W2 (split-K=2; bias b2 + gelu in residual) -> abuf
  gemm_nt<float, false, false><<<dim3(384, 1, 2), blk, 0, stream>>>(
      f1, 3072, 1536, wA + 3072 * 768, 3072, 1536, nullptr, 0, abuf, 768, 6291456, 6, 1536);

  // y = ln2(y + gelu(f + b2))
  residual_stats<true><<<dim3(96, 8), blk, 0, stream>>>(y, abuf, p1, b2, part);
  ln_apply<false><<<dim3(6144), blk, 0, stream>>>(y, nullptr, ln2w, ln2b, part);
}